// Round 7
// baseline (118.749 us; speedup 1.0000x reference)
//
#include <hip/hip_runtime.h>
#include <math.h>

constexpr int B_ = 4, C_ = 32, L_ = 256, M_ = 256, F_ = 8, N_ = 64;

// One (b, l-pair) per 256-thread block (4 waves). Thread owns one (l, m-pair)
// site: half = tid>>7 selects l = 2*lpair+half, t = tid&127 -> m = 2t,2t+1
// (float2). Each thread reduces ALL 32 c itself -> zero cross-wave combine
// (R6 showed combine overhead regresses). Block reads 2 KB contiguous per c
// (two adjacent 1 KB rows), and adjacent blocks cover adjacent l-pairs, so
// the chip sweeps each 256 KB (b,c) plane as long sequential slabs instead of
// scattered power-of-2-strided 1 KB rows (suspected HBM channel aliasing).
// Acc = 8f*2(r/i)*float2 = 32 floats; LB(256,4) -> 128 VGPR cap, no spill.
// Grid 512 x 4 waves = 8 waves/CU.
__global__ __launch_bounds__(256, 4) void sphereconv_kernel(
    const float* __restrict__ xr, const float* __restrict__ xi,
    const float* __restrict__ wr, const float* __restrict__ wi,
    float* __restrict__ out)
{
    __shared__ float ws[2][C_ * 16];   // per-l interpolated weights [c][wr f0..7 | wi f0..7]

    const int b     = blockIdx.x >> 7;         // / (L/2)
    const int lpair = blockIdx.x & 127;
    const int l0    = lpair * 2;
    const int tid   = threadIdx.x;             // 0..255
    const int half  = tid >> 7;                // which l of the pair
    const int t     = tid & 127;               // m-pair index
    const int l     = l0 + half;

    // stage 2*512 interpolated weight floats: 4 per thread
#pragma unroll
    for (int i = tid; i < 2 * C_ * 16; i += 256) {
        const int li = i >> 9;                 // 0/1
        const int r  = i & 511;
        const int c  = r >> 4;
        const int j  = r & 15;
        const int f  = j & 7;
        const int ll = l0 + li;
        const float tc = ((float)ll / (float)(L_ - 1)) * (float)(N_ - 1);
        int lo = (int)floorf(tc);
        if (lo > N_ - 2) lo = N_ - 2;
        const float frac = tc - (float)lo;
        const float* w = (j & 8) ? wi : wr;
        const int base = (f * C_ + c) * N_ + lo;   // w layout (F,C,N,1)
        ws[li][c * 16 + j] = w[base] * (1.0f - frac) + w[base + 1] * frac;
    }
    __syncthreads();

    float2 accr[F_], acci[F_];
#pragma unroll
    for (int f = 0; f < F_; ++f) {
        accr[f] = make_float2(0.f, 0.f);
        acci[f] = make_float2(0.f, 0.f);
    }

    const size_t strideC2 = (size_t)L_ * M_ / 2;   // c-stride in float2 units
    const size_t xoff = ((size_t)b * C_) * L_ * M_ + (size_t)l * M_ + t * 2;
    const float2* xr2 = (const float2*)(xr + xoff);
    const float2* xi2 = (const float2*)(xi + xoff);
    const float* wsl = ws[half];

#define CX(f, A, Bv)                                          \
    accr[f].x = fmaf(A, vr.x, fmaf(-(Bv), vi.x, accr[f].x));  \
    accr[f].y = fmaf(A, vr.y, fmaf(-(Bv), vi.y, accr[f].y));  \
    acci[f].x = fmaf(A, vi.x, fmaf((Bv), vr.x, acci[f].x));   \
    acci[f].y = fmaf(A, vi.y, fmaf((Bv), vr.y, acci[f].y));

#pragma unroll 8
    for (int c = 0; c < C_; ++c) {
        const float2 vr = xr2[c * strideC2];
        const float2 vi = xi2[c * strideC2];
        const float* wp = &wsl[c * 16];
        const float4 a0 = *(const float4*)(wp + 0);   // wr f0..3
        const float4 a1 = *(const float4*)(wp + 4);   // wr f4..7
        const float4 b0 = *(const float4*)(wp + 8);   // wi f0..3
        const float4 b1 = *(const float4*)(wp + 12);  // wi f4..7
        CX(0, a0.x, b0.x)
        CX(1, a0.y, b0.y)
        CX(2, a0.z, b0.z)
        CX(3, a0.w, b0.w)
        CX(4, a1.x, b1.x)
        CX(5, a1.y, b1.y)
        CX(6, a1.z, b1.z)
        CX(7, a1.w, b1.w)
    }
#undef CX

    const float scale = sqrtf(1.0f + (float)l) * (1.0f / (float)C_);
    // out layout: (((s*B + b)*F + f)*L + l)*M + m ; s=0 real(relu), s=1 imag
    const size_t o0      = (((size_t)b * F_) * L_ + l) * M_ + t * 2;
    const size_t imagOff = (size_t)B_ * F_ * L_ * M_;
    const size_t fStride = (size_t)L_ * M_;
#pragma unroll
    for (int f = 0; f < F_; ++f) {
        float2 yr, yi;
        yr.x = fmaxf(accr[f].x * scale, 0.f);
        yr.y = fmaxf(accr[f].y * scale, 0.f);
        yi.x = acci[f].x * scale;
        yi.y = acci[f].y * scale;
        *(float2*)(out + o0 + (size_t)f * fStride)           = yr;
        *(float2*)(out + o0 + (size_t)f * fStride + imagOff) = yi;
    }
}

extern "C" void kernel_launch(void* const* d_in, const int* in_sizes, int n_in,
                              void* d_out, int out_size, void* d_ws, size_t ws_size,
                              hipStream_t stream) {
    const float* xr = (const float*)d_in[0];
    const float* xi = (const float*)d_in[1];
    const float* wr = (const float*)d_in[2];
    const float* wi = (const float*)d_in[3];
    float* out = (float*)d_out;
    sphereconv_kernel<<<dim3(B_ * L_ / 2), dim3(256), 0, stream>>>(xr, xi, wr, wi, out);
}

// Round 8
// 110.167 us; speedup vs baseline: 1.0779x; 1.0779x over previous
//
#include <hip/hip_runtime.h>
#include <math.h>

constexpr int B_ = 4, C_ = 32, L_ = 256, M_ = 256, F_ = 8, N_ = 64;

// One (b,l) per 256-thread block (4 waves). Wave w owns f = {2w, 2w+1} and
// reduces ALL 32 c itself; lane owns m4-site (float4 = 1 KB/wave-load).
// f-split => zero cross-wave combine (R4/R6 showed combine eats the TLP win)
// while keeping float4 width (R5's proven +7us) AND high TLP: acc = 32 floats
// -> ~70-85 VGPR -> 5-7 blocks/CU = 20-28 waves/CU real occupancy.
// The 4 waves read identical x lines: 4x L1-side redundancy, absorbed by
// L1/L2 (L2 traffic unchanged at ~64 MB). LB(256,4) caps allocator at 128
// VGPR (prevents R2's default-60 spill) without binding real occupancy.
__global__ __launch_bounds__(256, 4) void sphereconv_kernel(
    const float* __restrict__ xr, const float* __restrict__ xi,
    const float* __restrict__ wr, const float* __restrict__ wi,
    float* __restrict__ out)
{
    __shared__ float ws[C_ * 16];   // [c][ wr f0..7 | wi f0..7 ]

    const int b    = blockIdx.x >> 8;        // / L_
    const int l    = blockIdx.x & (L_ - 1);
    const int tid  = threadIdx.x;            // 0..255
    const int w    = tid >> 6;               // wave id 0..3 -> f pair {2w, 2w+1}
    const int lane = tid & 63;               // m4 site

    // interp coords (uniform): t = l/(L-1)*(N-1)
    const float tc = ((float)l / (float)(L_ - 1)) * (float)(N_ - 1);
    int lo = (int)floorf(tc);
    if (lo > N_ - 2) lo = N_ - 2;
    const float frac = tc - (float)lo;

    // stage 512 interpolated weight floats: 2 per thread
#pragma unroll
    for (int i = tid; i < C_ * 16; i += 256) {
        const int c = i >> 4;
        const int j = i & 15;
        const int f = j & 7;
        const float* wptr = (j & 8) ? wi : wr;
        const int base = (f * C_ + c) * N_ + lo;   // w layout (F,C,N,1)
        ws[c * 16 + j] = wptr[base] * (1.0f - frac) + wptr[base + 1] * frac;
    }
    __syncthreads();

    const size_t strideC4 = (size_t)L_ * M_ / 4;   // c-stride in float4 units
    const size_t xoff = ((size_t)b * C_) * L_ * M_ + (size_t)l * M_ + lane * 4;
    const float4* xr4 = (const float4*)(xr + xoff);
    const float4* xi4 = (const float4*)(xi + xoff);

    float4 ar0 = {0,0,0,0}, ai0 = {0,0,0,0};   // f = 2w
    float4 ar1 = {0,0,0,0}, ai1 = {0,0,0,0};   // f = 2w+1

#pragma unroll 8
    for (int c = 0; c < C_; ++c) {
        const float4 vr = xr4[c * strideC4];
        const float4 vi = xi4[c * strideC4];
        const float2 wrp = *(const float2*)&ws[c * 16 + 2 * w];      // wr f=2w,2w+1
        const float2 wip = *(const float2*)&ws[c * 16 + 8 + 2 * w];  // wi f=2w,2w+1

        ar0.x = fmaf(wrp.x, vr.x, fmaf(-wip.x, vi.x, ar0.x));
        ar0.y = fmaf(wrp.x, vr.y, fmaf(-wip.x, vi.y, ar0.y));
        ar0.z = fmaf(wrp.x, vr.z, fmaf(-wip.x, vi.z, ar0.z));
        ar0.w = fmaf(wrp.x, vr.w, fmaf(-wip.x, vi.w, ar0.w));
        ai0.x = fmaf(wrp.x, vi.x, fmaf( wip.x, vr.x, ai0.x));
        ai0.y = fmaf(wrp.x, vi.y, fmaf( wip.x, vr.y, ai0.y));
        ai0.z = fmaf(wrp.x, vi.z, fmaf( wip.x, vr.z, ai0.z));
        ai0.w = fmaf(wrp.x, vi.w, fmaf( wip.x, vr.w, ai0.w));

        ar1.x = fmaf(wrp.y, vr.x, fmaf(-wip.y, vi.x, ar1.x));
        ar1.y = fmaf(wrp.y, vr.y, fmaf(-wip.y, vi.y, ar1.y));
        ar1.z = fmaf(wrp.y, vr.z, fmaf(-wip.y, vi.z, ar1.z));
        ar1.w = fmaf(wrp.y, vr.w, fmaf(-wip.y, vi.w, ar1.w));
        ai1.x = fmaf(wrp.y, vi.x, fmaf( wip.y, vr.x, ai1.x));
        ai1.y = fmaf(wrp.y, vi.y, fmaf( wip.y, vr.y, ai1.y));
        ai1.z = fmaf(wrp.y, vi.z, fmaf( wip.y, vr.z, ai1.z));
        ai1.w = fmaf(wrp.y, vi.w, fmaf( wip.y, vr.w, ai1.w));
    }

    const float scale = sqrtf(1.0f + (float)l) * (1.0f / (float)C_);
    // out layout: (((s*B + b)*F + f)*L + l)*M + m ; s=0 real(relu), s=1 imag
    const int   f0      = 2 * w;
    const size_t o0      = (((size_t)b * F_ + f0) * L_ + l) * M_ + lane * 4;
    const size_t imagOff = (size_t)B_ * F_ * L_ * M_;
    const size_t fStride = (size_t)L_ * M_;

    float4 yr0, yi0, yr1, yi1;
    yr0.x = fmaxf(ar0.x * scale, 0.f); yr0.y = fmaxf(ar0.y * scale, 0.f);
    yr0.z = fmaxf(ar0.z * scale, 0.f); yr0.w = fmaxf(ar0.w * scale, 0.f);
    yi0.x = ai0.x * scale; yi0.y = ai0.y * scale;
    yi0.z = ai0.z * scale; yi0.w = ai0.w * scale;
    yr1.x = fmaxf(ar1.x * scale, 0.f); yr1.y = fmaxf(ar1.y * scale, 0.f);
    yr1.z = fmaxf(ar1.z * scale, 0.f); yr1.w = fmaxf(ar1.w * scale, 0.f);
    yi1.x = ai1.x * scale; yi1.y = ai1.y * scale;
    yi1.z = ai1.z * scale; yi1.w = ai1.w * scale;

    *(float4*)(out + o0)                      = yr0;
    *(float4*)(out + o0 + imagOff)            = yi0;
    *(float4*)(out + o0 + fStride)            = yr1;
    *(float4*)(out + o0 + fStride + imagOff)  = yi1;
}

extern "C" void kernel_launch(void* const* d_in, const int* in_sizes, int n_in,
                              void* d_out, int out_size, void* d_ws, size_t ws_size,
                              hipStream_t stream) {
    const float* xr = (const float*)d_in[0];
    const float* xi = (const float*)d_in[1];
    const float* wr = (const float*)d_in[2];
    const float* wi = (const float*)d_in[3];
    float* out = (float*)d_out;
    sphereconv_kernel<<<dim3(B_ * L_), dim3(256), 0, stream>>>(xr, xi, wr, wi, out);
}